// Round 4
// baseline (283.458 us; speedup 1.0000x reference)
//
#include <hip/hip_runtime.h>
#include <cstdint>

// MultiHeadAttention: B=4, S=2048, D=1024, H=16, HD=64. fp32 in/out, bf16 MFMA compute.
// R13: attn restructured for occupancy: 8 waves x 32 q-rows (512 thr), Q-tile 256,
// sP 4KB/wave -> LDS 64KB/block, 2 blocks/CU = 16 waves/CU (was 8). Single
// __syncthreads per iter (R12 double-barrier measured neutral-negative, reverted).
// QKV gemm (8-phase 256^2) and out-proj gemm_bt unchanged.

#define B_ 4
#define S_ 2048
#define D_ 1024
#define H_ 16
#define HD_ 64
#define QKV_N 3072
#define QK_LD 2048  // q|k buffer row stride (V lives in vt)
#define SCALE_Q 0.18033688011111772f  // 0.125 * log2(e)

typedef __bf16 bf16x8 __attribute__((ext_vector_type(8)));
typedef __bf16 bf16x2 __attribute__((ext_vector_type(2)));
typedef float f32x4 __attribute__((ext_vector_type(4)));
typedef short short8 __attribute__((ext_vector_type(8)));

__device__ __forceinline__ unsigned short f2bf(float f) {
  unsigned int u = __builtin_bit_cast(unsigned int, f);
  u = (u + 0x7FFFu + ((u >> 16) & 1u)) >> 16;  // RNE
  return (unsigned short)u;
}

__device__ __forceinline__ unsigned int pkbf(float a, float b) {
  bf16x2 v;
  v.x = (__bf16)a;
  v.y = (__bf16)b;
  return __builtin_bit_cast(unsigned int, v);
}

__device__ __forceinline__ void gload16(const void* g, void* l) {
  __builtin_amdgcn_global_load_lds(
      (const __attribute__((address_space(1))) void*)g,
      (__attribute__((address_space(3))) void*)l, 16, 0, 0);
}

__global__ __launch_bounds__(256) void cvt_bf16(const float* __restrict__ in,
                                                unsigned short* __restrict__ out, int n8) {
  int i = blockIdx.x * 256 + threadIdx.x;
  if (i >= n8) return;
  const float4* p = (const float4*)in + (size_t)i * 2;
  float4 a = p[0], b = p[1];
  unsigned short o[8] = {f2bf(a.x), f2bf(a.y), f2bf(a.z), f2bf(a.w),
                         f2bf(b.x), f2bf(b.y), f2bf(b.z), f2bf(b.w)};
  *(uint4*)(out + (size_t)i * 8) = *(const uint4*)o;
}

__global__ __launch_bounds__(256) void cvt_w4(const float* __restrict__ w0, const float* __restrict__ w1,
                                              const float* __restrict__ w2, const float* __restrict__ w3,
                                              unsigned short* __restrict__ dst) {
  int y = blockIdx.y;
  const float* src = (y == 0) ? w0 : (y == 1) ? w1 : (y == 2) ? w2 : w3;
  float s = (y == 0) ? SCALE_Q : 1.0f;
  int i = blockIdx.x * 256 + threadIdx.x;
  const float4* p = (const float4*)src + (size_t)i * 2;
  float4 a = p[0], b = p[1];
  unsigned short o[8] = {f2bf(a.x * s), f2bf(a.y * s), f2bf(a.z * s), f2bf(a.w * s),
                         f2bf(b.x * s), f2bf(b.y * s), f2bf(b.z * s), f2bf(b.w * s)};
  *(uint4*)(dst + (size_t)y * 1048576 + (size_t)i * 8) = *(const uint4*)o;
}

__global__ __launch_bounds__(256) void bias_cat(const float* __restrict__ bq, const float* __restrict__ bk,
                                                const float* __restrict__ bv, float* __restrict__ bcat) {
  int i = blockIdx.x * 256 + threadIdx.x;
  float v = (i < 1024) ? bq[i] * SCALE_Q : (i < 2048) ? bk[i - 1024] : bv[i - 2048];
  bcat[i] = v;
}

// ---------------- 256x256 8-phase QKV GEMM (unchanged) ----------------
__device__ __forceinline__ void ld_afrag(const unsigned short* s, int rowbase, int quad,
                                         int sw, bf16x8 af[4][2]) {
#pragma unroll
  for (int mi2 = 0; mi2 < 4; ++mi2) {
    int row = rowbase + mi2 * 16;
#pragma unroll
    for (int kk = 0; kk < 2; ++kk)
      af[mi2][kk] = *(const bf16x8*)&s[row * 64 + ((((kk << 2) + quad) ^ sw) << 3)];
  }
}

__device__ __forceinline__ void ld_bfrag(const unsigned short* s, int rowbase, int quad,
                                         int sw, bf16x8 bf[2][2]) {
#pragma unroll
  for (int ni2 = 0; ni2 < 2; ++ni2) {
    int row = rowbase + ni2 * 16;
#pragma unroll
    for (int kk = 0; kk < 2; ++kk)
      bf[ni2][kk] = *(const bf16x8*)&s[row * 64 + ((((kk << 2) + quad) ^ sw) << 3)];
  }
}

#define SBAR() __builtin_amdgcn_sched_barrier(0)
#define BARRIER()                      \
  do {                                 \
    SBAR();                            \
    __builtin_amdgcn_s_barrier();      \
    SBAR();                            \
  } while (0)
#define WAITLGKM()                                      \
  do {                                                  \
    asm volatile("s_waitcnt lgkmcnt(0)" ::: "memory");  \
    SBAR();                                             \
  } while (0)

#define MM(qm, qn, BF)                                                                   \
  _Pragma("unroll") for (int mi2 = 0; mi2 < 4; ++mi2)                                    \
  _Pragma("unroll") for (int ni2 = 0; ni2 < 2; ++ni2)                                    \
  _Pragma("unroll") for (int kk = 0; kk < 2; ++kk)                                       \
      acc[(qm) * 4 + mi2][(qn) * 2 + ni2] = __builtin_amdgcn_mfma_f32_16x16x32_bf16(     \
          af[mi2][kk], BF[ni2][kk], acc[(qm) * 4 + mi2][(qn) * 2 + ni2], 0, 0, 0);

__global__ __launch_bounds__(512, 2) void gemm_qkv_256(
    const unsigned short* __restrict__ A, const unsigned short* __restrict__ W,
    const float* __restrict__ bias, unsigned short* __restrict__ qk,
    unsigned short* __restrict__ vt) {
  __shared__ __attribute__((aligned(16))) unsigned short sA[2][256 * 64];
  __shared__ __attribute__((aligned(16))) unsigned short sB[2][256 * 64];

  const int t = threadIdx.x;
  const int lane = t & 63;
  const int w = t >> 6;
  const int lm = lane & 15;
  const int quad = lane >> 4;
  const int sw = lm & 7;
  const int wm = (w >> 2) * 128;
  const int wn = (w & 3) * 64;

  const int bid = blockIdx.x;
  const int xcd = bid & 7, lin = bid >> 3;
  const int mt = xcd * 4 + (lin & 3);
  const int nt = lin >> 2;
  const int m0 = mt * 256, n0 = nt * 256;
  const int K = 1024;

  const int srow = t >> 3;
  const int scol = ((t & 7) ^ ((t >> 3) & 7)) << 3;
  const unsigned short* Ab = A + ((size_t)m0 + srow) * K + scol;
  const unsigned short* Wb = W + ((size_t)n0 + srow) * K + scol;

#define STG_A(bb, q, kt) gload16(Ab + (size_t)((q) * 64) * K + (kt), &sA[bb][(q) * 4096 + w * 512])
#define STG_B(bb, q, kt) gload16(Wb + (size_t)((q) * 64) * K + (kt), &sB[bb][(q) * 4096 + w * 512])

  STG_A(0, 0, 0); STG_A(0, 1, 0); STG_A(0, 2, 0); STG_A(0, 3, 0);
  STG_B(0, 0, 0); STG_B(0, 1, 0); STG_B(0, 2, 0); STG_B(0, 3, 0);
  STG_A(1, 0, 64); STG_A(1, 2, 64);
  STG_B(1, 0, 64); STG_B(1, 1, 64);
  STG_A(1, 1, 64); STG_A(1, 3, 64);
  asm volatile("s_waitcnt vmcnt(6)" ::: "memory");
  BARRIER();

  f32x4 acc[8][4] = {};
  bf16x8 af[4][2], bf0[2][2], bf1[2][2];

#define GROUP(c, kn1, kn2)                                                            \
  do {                                                                                \
    ld_afrag(sA[c], wm + lm, quad, sw, af);                                           \
    ld_bfrag(sB[c], wn + lm, quad, sw, bf0);                                          \
    STG_B(c ^ 1, 2, kn1);                                                             \
    STG_B(c ^ 1, 3, kn1);                                                             \
    BARRIER(); WAITLGKM();                                                            \
    __builtin_amdgcn_s_setprio(1); MM(0, 0, bf0); __builtin_amdgcn_s_setprio(0);      \
    BARRIER();                                                                        \
    ld_bfrag(sB[c], wn + 32 + lm, quad, sw, bf1);                                     \
    STG_A(c, 0, kn2);                                                                 \
    STG_A(c, 2, kn2);                                                                 \
    BARRIER(); WAITLGKM();                                                            \
    __builtin_amdgcn_s_setprio(1); MM(0, 1, bf1); __builtin_amdgcn_s_setprio(0);      \
    BARRIER();                                                                        \
    ld_afrag(sA[c], wm + 64 + lm, quad, sw, af);                                      \
    STG_B(c, 0, kn2);                                                                 \
    STG_B(c, 1, kn2);                                                                 \
    BARRIER(); WAITLGKM();                                                            \
    __builtin_amdgcn_s_setprio(1); MM(1, 0, bf0); __builtin_amdgcn_s_setprio(0);      \
    BARRIER();                                                                        \
    STG_A(c, 1, kn2);                                                                 \
    STG_A(c, 3, kn2);                                                                 \
    asm volatile("s_waitcnt vmcnt(6)" ::: "memory");                                  \
    BARRIER();                                                                        \
    __builtin_amdgcn_s_setprio(1); MM(1, 1, bf1); __builtin_amdgcn_s_setprio(0);      \
    BARRIER();                                                                        \
  } while (0)

  for (int kt = 0; kt < K; kt += 128) {
    const int kn1a = kt + 64;
    const int kn2a = (kt + 128 < K) ? kt + 128 : K - 64;
    const int kn1b = kn2a;
    const int kn2b = (kt + 192 < K) ? kt + 192 : K - 64;
    GROUP(0, kn1a, kn2a);
    GROUP(1, kn1b, kn2b);
  }

  asm volatile("s_waitcnt vmcnt(0)" ::: "memory");

#pragma unroll
  for (int mi = 0; mi < 8; ++mi) {
    const int rbase = m0 + wm + mi * 16 + quad * 4;
#pragma unroll
    for (int ni = 0; ni < 4; ++ni) {
      const int col = n0 + wn + ni * 16 + lm;
      const float bv = bias[col];
      float v0 = acc[mi][ni][0] + bv, v1 = acc[mi][ni][1] + bv;
      float v2 = acc[mi][ni][2] + bv, v3 = acc[mi][ni][3] + bv;
      if (n0 < 2048) {
        qk[(size_t)(rbase + 0) * QK_LD + col] = f2bf(v0);
        qk[(size_t)(rbase + 1) * QK_LD + col] = f2bf(v1);
        qk[(size_t)(rbase + 2) * QK_LD + col] = f2bf(v2);
        qk[(size_t)(rbase + 3) * QK_LD + col] = f2bf(v3);
      } else {
        int c = col - 2048;
        int bh = (m0 >> 11) * 16 + (c >> 6);
        int hd = c & 63;
        int sbase = rbase & 2047;
        uint2 pk = {pkbf(v0, v1), pkbf(v2, v3)};
        *(uint2*)(vt + (size_t)bh * (HD_ * S_) + (size_t)hd * S_ + sbase) = pk;
      }
    }
  }
}

// ---------------- 128x128 gemm (out-proj only) ----------------
__global__ __launch_bounds__(256) void gemm_bt(
    const unsigned short* __restrict__ A, const unsigned short* __restrict__ W,
    const float* __restrict__ bias, void* __restrict__ Cout,
    unsigned short* __restrict__ vt, int M, int N, int K, int mode) {
  __shared__ __attribute__((aligned(16))) unsigned short sA[128 * 32];
  __shared__ __attribute__((aligned(16))) unsigned short sB[128 * 32];
  const int t = threadIdx.x;
  const int lane = t & 63;
  const int w = t >> 6;
  const int lm = lane & 15;
  const int quad = lane >> 4;
  const int m0 = blockIdx.x * 128;
  const int n0 = blockIdx.y * 128;
  const int wm = (w & 1) * 64;
  const int wn = (w >> 1) * 64;

  const int off0 = t * 8, off1 = t * 8 + 2048;
  const int ar0 = off0 >> 5, ac0 = (((off0 >> 3) & 3) ^ ((ar0 >> 1) & 3)) * 8;
  const int ar1 = off1 >> 5, ac1 = (((off1 >> 3) & 3) ^ ((ar1 >> 1) & 3)) * 8;
  const unsigned short* Ag0 = A + (size_t)(m0 + ar0) * K + ac0;
  const unsigned short* Ag1 = A + (size_t)(m0 + ar1) * K + ac1;
  const unsigned short* Wg0 = W + (size_t)(n0 + ar0) * K + ac0;
  const unsigned short* Wg1 = W + (size_t)(n0 + ar1) * K + ac1;
  unsigned short* sA0 = &sA[w * 512];
  unsigned short* sA1 = &sA[2048 + w * 512];
  unsigned short* sB0 = &sB[w * 512];
  unsigned short* sB1 = &sB[2048 + w * 512];

  f32x4 acc[4][4] = {};

  for (int kt = 0; kt < K; kt += 32) {
    gload16(Ag0 + kt, sA0);
    gload16(Ag1 + kt, sA1);
    gload16(Wg0 + kt, sB0);
    gload16(Wg1 + kt, sB1);
    __syncthreads();
    bf16x8 af[4], bf[4];
#pragma unroll
    for (int mi = 0; mi < 4; ++mi) {
      int row = wm + mi * 16 + lm;
      af[mi] = *(const bf16x8*)&sA[row * 32 + ((quad ^ ((row >> 1) & 3)) << 3)];
    }
#pragma unroll
    for (int ni = 0; ni < 4; ++ni) {
      int row = wn + ni * 16 + lm;
      bf[ni] = *(const bf16x8*)&sB[row * 32 + ((quad ^ ((row >> 1) & 3)) << 3)];
    }
#pragma unroll
    for (int mi = 0; mi < 4; ++mi)
#pragma unroll
      for (int ni = 0; ni < 4; ++ni)
        acc[mi][ni] = __builtin_amdgcn_mfma_f32_16x16x32_bf16(af[mi], bf[ni], acc[mi][ni], 0, 0, 0);
    __syncthreads();
  }

#pragma unroll
  for (int mi = 0; mi < 4; ++mi)
#pragma unroll
    for (int ni = 0; ni < 4; ++ni) {
      int col = n0 + wn + ni * 16 + lm;
      float bv = bias[col];
      float v0 = acc[mi][ni][0] + bv, v1 = acc[mi][ni][1] + bv;
      float v2 = acc[mi][ni][2] + bv, v3 = acc[mi][ni][3] + bv;
      int rbase = m0 + wm + mi * 16 + quad * 4;
      if (mode == 0) {
        float* op = (float*)Cout;
        op[(size_t)(rbase + 0) * N + col] = v0;
        op[(size_t)(rbase + 1) * N + col] = v1;
        op[(size_t)(rbase + 2) * N + col] = v2;
        op[(size_t)(rbase + 3) * N + col] = v3;
      } else if (col < 2048) {
        unsigned short* op = (unsigned short*)Cout;
        op[(size_t)(rbase + 0) * QK_LD + col] = f2bf(v0);
        op[(size_t)(rbase + 1) * QK_LD + col] = f2bf(v1);
        op[(size_t)(rbase + 2) * QK_LD + col] = f2bf(v2);
        op[(size_t)(rbase + 3) * QK_LD + col] = f2bf(v3);
      } else {
        int c = col - 2048;
        int bh = (m0 >> 11) * 16 + (c >> 6);
        int hd = c & 63;
        int sbase = (rbase & 2047);
        uint2 pk = {pkbf(v0, v1), pkbf(v2, v3)};
        *(uint2*)(vt + (size_t)bh * (HD_ * S_) + (size_t)hd * S_ + sbase) = pk;
      }
    }
}

// ---------------- flash attention (R13: 8 waves x 32 q-rows, 16 waves/CU) ----------------
// Block = (b,h) x 256 Q-rows; 512 threads = 8 waves, 32 q-rows/wave (mi=2).
// LDS: sK/sV dbuf 32KB + sP 4KB/wave = 64KB -> 2 blocks/CU = 16 waves/CU (4/SIMD):
// two INDEPENDENT blocks per CU fill each other's barrier/latency stalls.
// Staging: 512 threads cover a 64x64 tile in one gload16 each (K and V).
// Single __syncthreads per iter (R11 structure; R12 double-barrier was a measured loss).
__global__ __launch_bounds__(512, 4) void attn_kernel(
    const unsigned short* __restrict__ qk, const unsigned short* __restrict__ vt,
    unsigned short* __restrict__ ab) {
  __shared__ __attribute__((aligned(16))) unsigned short sK[2][64 * 64];
  __shared__ __attribute__((aligned(16))) unsigned short sV[2][64 * 64];  // [hd][n]
  __shared__ __attribute__((aligned(16))) unsigned short sP[8][32 * 64];  // 4KB/wave

  const int t = threadIdx.x;
  const int lane = t & 63;
  const int w = t >> 6;  // 0..7
  const int lm = lane & 15;
  const int quad = lane >> 4;
  const int bh = blockIdx.x & 63;
  const int b = bh >> 4, h = bh & 15;
  const int q0 = (blockIdx.x >> 6) * 256;

  const unsigned short* qg = qk + (size_t)b * S_ * QK_LD + h * HD_;
  const unsigned short* kg = qg + 1024;
  const unsigned short* vg = vt + (size_t)bh * HD_ * S_;

  // one gload16 per thread covers a full 64x64 tile: row = t>>3, pre-swizzled chunk
  const int r0 = t >> 3;
  const int c0 = ((t & 7) ^ (r0 & 7)) * 8;

  // stage K0/V0; load Q frags straight to registers meanwhile
  gload16(kg + (size_t)r0 * QK_LD + c0, &sK[0][w * 512]);
  gload16(vg + (size_t)r0 * S_ + c0, &sV[0][w * 512]);

  bf16x8 qf[2][2];
#pragma unroll
  for (int mi = 0; mi < 2; ++mi) {
    int row = q0 + w * 32 + mi * 16 + lm;
#pragma unroll
    for (int kc = 0; kc < 2; ++kc)
      qf[mi][kc] = *(const bf16x8*)(qg + (size_t)row * QK_LD + kc * 32 + quad * 8);
  }
  __syncthreads();  // K0/V0 staged

  unsigned short* sPw = sP[w];
  const bf16x8 ones = __builtin_bit_cast(bf16x8, (short8)(short)0x3F80);  // 1.0 bf16
  f32x4 o[2][4] = {};
  f32x4 Lacc[2] = {};

  for (int n0 = 0; n0 < S_; n0 += 64) {
    const int cur = (n0 >> 6) & 1, nxt = cur ^ 1;
    if (n0 + 64 < S_) {  // prefetch next K/V tile (wave-uniform branch)
      gload16(kg + (size_t)(n0 + 64 + r0) * QK_LD + c0, &sK[nxt][w * 512]);
      gload16(vg + (size_t)r0 * S_ + (n0 + 64) + c0, &sV[nxt][w * 512]);
    }

    // S^T[key][q-row]: A = K (lane = key), B = Q (lane = q-row).
    f32x4 s[2][4] = {};
#pragma unroll
    for (int kc = 0; kc < 2; ++kc)
#pragma unroll
      for (int nb = 0; nb < 4; ++nb) {
        int row = nb * 16 + lm;
        bf16x8 kf = *(const bf16x8*)&sK[cur][row * 64 + (((kc * 4 + quad) ^ (row & 7)) << 3)];
#pragma unroll
        for (int mi = 0; mi < 2; ++mi)
          s[mi][nb] = __builtin_amdgcn_mfma_f32_16x16x32_bf16(kf, qf[mi][kc], s[mi][nb], 0, 0, 0);
      }

    // exp2 + pk-cvt 4 consecutive keys -> one ds_write_b64 per (mi, nb).
#pragma unroll
    for (int mi = 0; mi < 2; ++mi) {
      int prow = mi * 16 + lm;
      char* rowp = (char*)sPw + prow * 128;
#pragma unroll
      for (int nb = 0; nb < 4; ++nb) {
        const f32x4& sv = s[mi][nb];
        uint2 pk = {pkbf(__builtin_amdgcn_exp2f(sv[0]), __builtin_amdgcn_exp2f(sv[1])),
                    pkbf(__builtin_amdgcn_exp2f(sv[2]), __builtin_amdgcn_exp2f(sv[3]))};
        int c16 = (nb * 2 + (quad >> 1)) ^ (prow & 7);
        *(uint2*)(rowp + (c16 << 4) + ((quad & 1) << 3)) = pk;
      }
    }

    // PV + L. pf = A-frag of P (lane m=lm, keys quad*8..+7 within kc half).
#pragma unroll
    for (int kc = 0; kc < 2; ++kc) {
      bf16x8 pf[2];
#pragma unroll
      for (int mi = 0; mi < 2; ++mi) {
        int prow = mi * 16 + lm;
        pf[mi] = *(const bf16x8*)&sPw[prow * 64 + (((kc * 4 + quad) ^ (prow & 7)) << 3)];
        Lacc[mi] = __builtin_amdgcn_mfma_f32_16x16x32_bf16(pf[mi], ones, Lacc[mi], 0, 0, 0);
      }
#pragma unroll
      for (int nf = 0; nf < 4; ++nf) {
        int row = nf * 16 + lm;
        bf16x8 vf = *(const bf16x8*)&sV[cur][row * 64 + (((kc * 4 + quad) ^ (row & 7)) << 3)];
#pragma unroll
        for (int mi = 0; mi < 2; ++mi)
          o[mi][nf] = __builtin_amdgcn_mfma_f32_16x16x32_bf16(pf[mi], vf, o[mi][nf], 0, 0, 0);
      }
    }
    __syncthreads();  // publishes prefetch + protects cur-buffer reuse
  }

#pragma unroll
  for (int mi = 0; mi < 2; ++mi)
#pragma unroll
    for (int r = 0; r < 4; ++r) {
      float rinv = 1.0f / Lacc[mi][r];
      int row = q0 + w * 32 + mi * 16 + quad * 4 + r;
#pragma unroll
      for (int nf = 0; nf < 4; ++nf) {
        int col = h * HD_ + nf * 16 + lm;
        ab[(size_t)(b * S_ + row) * D_ + col] = f2bf(o[mi][nf][r] * rinv);
      }
    }
}

extern "C" void kernel_launch(void* const* d_in, const int* in_sizes, int n_in,
                              void* d_out, int out_size, void* d_ws, size_t ws_size,
                              hipStream_t stream) {
  const float* x = (const float*)d_in[0];
  const float* Wq = (const float*)d_in[1];
  const float* bq = (const float*)d_in[2];
  const float* Wk = (const float*)d_in[3];
  const float* bk = (const float*)d_in[4];
  const float* Wv = (const float*)d_in[5];
  const float* bv = (const float*)d_in[6];
  const float* Wo = (const float*)d_in[7];
  const float* bo = (const float*)d_in[8];
  float* out = (float*)d_out;

  const size_t E = (size_t)B_ * S_ * D_;   // 8388608
  const size_t WE = (size_t)D_ * D_;       // 1048576
  unsigned short* xb = (unsigned short*)d_ws;
  unsigned short* wcat = xb + E;
  unsigned short* wob = wcat + 3 * WE;
  float* bcat = (float*)(wcat + 4 * WE);
  unsigned short* qkb = (unsigned short*)(bcat + 4096);
  unsigned short* vtb = qkb + (size_t)B_ * S_ * QK_LD;
  unsigned short* abuf = xb;  // reuse: x consumed by QKV gemm before attention writes

  cvt_bf16<<<dim3((unsigned)(E / 8 / 256)), 256, 0, stream>>>(x, xb, (int)(E / 8));
  cvt_w4<<<dim3(512, 4), 256, 0, stream>>>(Wq, Wk, Wv, Wo, wcat);
  bias_cat<<<dim3(12), 256, 0, stream>>>(bq, bk, bv, bcat);

  gemm_qkv_256<<<dim3(384), 512, 0, stream>>>(xb, wcat, bcat, qkb, vtb);
  attn_kernel<<<dim3(512), 512, 0, stream>>>(qkb, vtb, abuf);
  gemm_bt<<<dim3((B_ * S_) / 128, D_ / 128), 256, 0, stream>>>(
      abuf, wob, bo, out, nullptr, B_ * S_, D_, D_, 0);
}

// Round 5
// 276.483 us; speedup vs baseline: 1.0252x; 1.0252x over previous
//
#include <hip/hip_runtime.h>
#include <cstdint>

// MultiHeadAttention: B=4, S=2048, D=1024, H=16, HD=64. fp32 in/out, bf16 MFMA compute.
// R14: (1) gemm_qkv K-loop flattened to 2 fat phases / 2 barriers per BK=64 tile with
// exact counted vmcnt(8) (was 4 phases / 8 barriers / vmcnt(6)); (2) cvt_bf16+cvt_w4+
// bias_cat fused into one cvt_all kernel (fewer graph launches).
// attn (R13 8-wave/32-row) and out-proj gemm_bt unchanged.

#define B_ 4
#define S_ 2048
#define D_ 1024
#define H_ 16
#define HD_ 64
#define QKV_N 3072
#define QK_LD 2048  // q|k buffer row stride (V lives in vt)
#define SCALE_Q 0.18033688011111772f  // 0.125 * log2(e)

typedef __bf16 bf16x8 __attribute__((ext_vector_type(8)));
typedef __bf16 bf16x2 __attribute__((ext_vector_type(2)));
typedef float f32x4 __attribute__((ext_vector_type(4)));
typedef short short8 __attribute__((ext_vector_type(8)));

__device__ __forceinline__ unsigned short f2bf(float f) {
  unsigned int u = __builtin_bit_cast(unsigned int, f);
  u = (u + 0x7FFFu + ((u >> 16) & 1u)) >> 16;  // RNE
  return (unsigned short)u;
}

__device__ __forceinline__ unsigned int pkbf(float a, float b) {
  bf16x2 v;
  v.x = (__bf16)a;
  v.y = (__bf16)b;
  return __builtin_bit_cast(unsigned int, v);
}

__device__ __forceinline__ void gload16(const void* g, void* l) {
  __builtin_amdgcn_global_load_lds(
      (const __attribute__((address_space(1))) void*)g,
      (__attribute__((address_space(3))) void*)l, 16, 0, 0);
}

// Fused elementwise front-end: blocks [0,4096) cvt x -> bf16; [4096,6144) cvt 4 W mats;
// block 6144 builds bias_cat. All paths vectorized float4 x2 -> ushort8.
__global__ __launch_bounds__(256) void cvt_all(
    const float* __restrict__ x, const float* __restrict__ w0, const float* __restrict__ w1,
    const float* __restrict__ w2, const float* __restrict__ w3,
    const float* __restrict__ bq, const float* __restrict__ bk, const float* __restrict__ bv,
    unsigned short* __restrict__ xb, unsigned short* __restrict__ wcat,
    float* __restrict__ bcat) {
  const int blk = blockIdx.x;
  const int t = threadIdx.x;
  if (blk < 4096) {  // x: 8388608 elems = 4096*256*8
    size_t i = (size_t)blk * 256 + t;
    const float4* p = (const float4*)x + i * 2;
    float4 a = p[0], b = p[1];
    unsigned short o[8] = {f2bf(a.x), f2bf(a.y), f2bf(a.z), f2bf(a.w),
                           f2bf(b.x), f2bf(b.y), f2bf(b.z), f2bf(b.w)};
    *(uint4*)(xb + i * 8) = *(const uint4*)o;
  } else if (blk < 6144) {  // weights: 4 mats x 512 blocks
    int y = (blk - 4096) >> 9;
    const float* src = (y == 0) ? w0 : (y == 1) ? w1 : (y == 2) ? w2 : w3;
    float s = (y == 0) ? SCALE_Q : 1.0f;
    size_t i = (size_t)((blk - 4096) & 511) * 256 + t;
    const float4* p = (const float4*)src + i * 2;
    float4 a = p[0], b = p[1];
    unsigned short o[8] = {f2bf(a.x * s), f2bf(a.y * s), f2bf(a.z * s), f2bf(a.w * s),
                           f2bf(b.x * s), f2bf(b.y * s), f2bf(b.z * s), f2bf(b.w * s)};
    *(uint4*)(wcat + (size_t)y * 1048576 + i * 8) = *(const uint4*)o;
  } else {  // bias concat: 3072 floats
    for (int i = t; i < 3072; i += 256) {
      float v = (i < 1024) ? bq[i] * SCALE_Q : (i < 2048) ? bk[i - 1024] : bv[i - 2048];
      bcat[i] = v;
    }
  }
}

// ---------------- 256x256 QKV GEMM, 2 fat phases / 2 barriers per BK=64 tile ----------------
// C[m,n] = sum_k A[m,k]*W[n,k] + bias[n]; A [8192][1024] bf16, W [3072][1024] bf16.
// 512 thr = 8 waves (2M x 4N), per-wave 128x64 out, BK=64, LDS 128KB dbuf.
// LDS rows 64 bf16 (128B): 16B-chunk index XOR (row&7); global source pre-swizzled.
// Per tile t (buf c=t&1):
//   issue 8 gload16 of tile t+1 -> buf c^1   (c^1's tile t-1 reads certified by prev
//                                             end-barrier, which precedes in prog order)
//   vmcnt(8)   -- retires exactly tile t's 8 loads (8 newer remain in flight)
//   BARRIER    -- publish tile t block-wide
//   P1: ds_read A-qm0 (8 b128) + B all (8 b128); lgkm(0); 32 MFMA
//   P2: ds_read A-qm1 (8 b128), B reused in regs; lgkm(0); 32 MFMA
//   BARRIER    -- all waves' reads of buf c done (lgkm(0) preceded MFMA) -> buf c may
//                 be DMA-overwritten by tile t+2's stage next iteration
// Tail: stage index clamps to last tile (redundant restage, never read) so the
// vmcnt(8) count stays exact every iteration.
__device__ __forceinline__ void ld_afrag(const unsigned short* s, int rowbase, int quad,
                                         int sw, bf16x8 af[4][2]) {
#pragma unroll
  for (int mi2 = 0; mi2 < 4; ++mi2) {
    int row = rowbase + mi2 * 16;
#pragma unroll
    for (int kk = 0; kk < 2; ++kk)
      af[mi2][kk] = *(const bf16x8*)&s[row * 64 + ((((kk << 2) + quad) ^ sw) << 3)];
  }
}

__device__ __forceinline__ void ld_bfrag4(const unsigned short* s, int rowbase, int quad,
                                          int sw, bf16x8 bf[4][2]) {
#pragma unroll
  for (int ni = 0; ni < 4; ++ni) {
    int row = rowbase + ni * 16;
#pragma unroll
    for (int kk = 0; kk < 2; ++kk)
      bf[ni][kk] = *(const bf16x8*)&s[row * 64 + ((((kk << 2) + quad) ^ sw) << 3)];
  }
}

#define SBAR() __builtin_amdgcn_sched_barrier(0)
#define BARRIER()                      \
  do {                                 \
    SBAR();                            \
    __builtin_amdgcn_s_barrier();      \
    SBAR();                            \
  } while (0)
#define WAITLGKM()                                      \
  do {                                                  \
    asm volatile("s_waitcnt lgkmcnt(0)" ::: "memory");  \
    SBAR();                                             \
  } while (0)

#define MM32(qm)                                                                         \
  _Pragma("unroll") for (int mi2 = 0; mi2 < 4; ++mi2)                                    \
  _Pragma("unroll") for (int ni = 0; ni < 4; ++ni)                                       \
  _Pragma("unroll") for (int kk = 0; kk < 2; ++kk)                                       \
      acc[(qm) * 4 + mi2][ni] = __builtin_amdgcn_mfma_f32_16x16x32_bf16(                 \
          af[mi2][kk], bf[ni][kk], acc[(qm) * 4 + mi2][ni], 0, 0, 0);

__global__ __launch_bounds__(512, 2) void gemm_qkv_256(
    const unsigned short* __restrict__ A, const unsigned short* __restrict__ W,
    const float* __restrict__ bias, unsigned short* __restrict__ qk,
    unsigned short* __restrict__ vt) {
  __shared__ __attribute__((aligned(16))) unsigned short sA[2][256 * 64];
  __shared__ __attribute__((aligned(16))) unsigned short sB[2][256 * 64];

  const int t = threadIdx.x;
  const int lane = t & 63;
  const int w = t >> 6;
  const int lm = lane & 15;
  const int quad = lane >> 4;
  const int sw = lm & 7;
  const int wm = (w >> 2) * 128;
  const int wn = (w & 3) * 64;

  // XCD patch swizzle: 384 blocks = 8 XCDs x 48; per XCD 4 m-tiles x 12 n-tiles.
  const int bid = blockIdx.x;
  const int xcd = bid & 7, lin = bid >> 3;
  const int mt = xcd * 4 + (lin & 3);
  const int nt = lin >> 2;
  const int m0 = mt * 256, n0 = nt * 256;
  const int K = 1024;

  const int srow = t >> 3;
  const int scol = ((t & 7) ^ ((t >> 3) & 7)) << 3;  // pre-swizzled global chunk
  const unsigned short* Ab = A + ((size_t)m0 + srow) * K + scol;
  const unsigned short* Wb = W + ((size_t)n0 + srow) * K + scol;

#define STG_A(bb, q, kt) gload16(Ab + (size_t)((q) * 64) * K + (kt), &sA[bb][(q) * 4096 + w * 512])
#define STG_B(bb, q, kt) gload16(Wb + (size_t)((q) * 64) * K + (kt), &sB[bb][(q) * 4096 + w * 512])
#define STG_TILE(bb, kt)                                              \
  do {                                                                \
    STG_A(bb, 0, kt); STG_A(bb, 1, kt); STG_A(bb, 2, kt); STG_A(bb, 3, kt); \
    STG_B(bb, 0, kt); STG_B(bb, 1, kt); STG_B(bb, 2, kt); STG_B(bb, 3, kt); \
  } while (0)

  // prologue: stage tile 0 only; iter 0 issues tile 1 and waits tile 0 via vmcnt(8)
  STG_TILE(0, 0);

  f32x4 acc[8][4] = {};
  bf16x8 af[4][2], bf[4][2];

  for (int tt = 0; tt < 16; ++tt) {
    const int c = tt & 1;
    const int kn = (tt + 1 < 16 ? tt + 1 : 15) * 64;  // clamped next-tile K offset
    STG_TILE(c ^ 1, kn);                              // tile t+1 (8 loads)
    asm volatile("s_waitcnt vmcnt(8)" ::: "memory");  // tile t resident (mine)
    BARRIER();                                        // publish tile t
    // P1: qm0 x all
    ld_afrag(sA[c], wm + lm, quad, sw, af);
    ld_bfrag4(sB[c], wn + lm, quad, sw, bf);
    WAITLGKM();
    __builtin_amdgcn_s_setprio(1); MM32(0); __builtin_amdgcn_s_setprio(0);
    // P2: qm1 x all (B frags reused from registers)
    ld_afrag(sA[c], wm + 64 + lm, quad, sw, af);
    WAITLGKM();
    __builtin_amdgcn_s_setprio(1); MM32(1); __builtin_amdgcn_s_setprio(0);
    BARRIER();  // reads of buf c complete -> safe to DMA-overwrite next iter
  }

  asm volatile("s_waitcnt vmcnt(0)" ::: "memory");  // drain clamped tail stage

  // epilogue: cols<2048 -> bf16 qk (stride 2048); cols>=2048 -> V transposed to vt
#pragma unroll
  for (int mi = 0; mi < 8; ++mi) {
    const int rbase = m0 + wm + mi * 16 + quad * 4;  // C row = quad*4 + reg
#pragma unroll
    for (int ni = 0; ni < 4; ++ni) {
      const int col = n0 + wn + ni * 16 + lm;
      const float bv = bias[col];
      float v0 = acc[mi][ni][0] + bv, v1 = acc[mi][ni][1] + bv;
      float v2 = acc[mi][ni][2] + bv, v3 = acc[mi][ni][3] + bv;
      if (n0 < 2048) {  // block-uniform
        qk[(size_t)(rbase + 0) * QK_LD + col] = f2bf(v0);
        qk[(size_t)(rbase + 1) * QK_LD + col] = f2bf(v1);
        qk[(size_t)(rbase + 2) * QK_LD + col] = f2bf(v2);
        qk[(size_t)(rbase + 3) * QK_LD + col] = f2bf(v3);
      } else {  // V: write transposed, 4 consecutive tokens -> one b64
        int c2 = col - 2048;
        int bh = (m0 >> 11) * 16 + (c2 >> 6);
        int hd = c2 & 63;
        int sbase = rbase & 2047;
        uint2 pk = {pkbf(v0, v1), pkbf(v2, v3)};
        *(uint2*)(vt + (size_t)bh * (HD_ * S_) + (size_t)hd * S_ + sbase) = pk;
      }
    }
  }
}

// ---------------- 128x128 gemm (out-proj only) ----------------
__global__ __launch_bounds__(256) void gemm_bt(
    const unsigned short* __restrict__ A, const unsigned short* __restrict__ W,
    const float* __restrict__ bias, void* __restrict__ Cout,
    unsigned short* __restrict__ vt, int M, int N, int K, int mode) {
  __shared__ __attribute__((aligned(16))) unsigned short sA[128 * 32];
  __shared__ __attribute__((aligned(16))) unsigned short sB[128 * 32];
  const int t = threadIdx.x;
  const int lane = t & 63;
  const int w = t >> 6;
  const int lm = lane & 15;
  const int quad = lane >> 4;
  const int m0 = blockIdx.x * 128;
  const int n0 = blockIdx.y * 128;
  const int wm = (w & 1) * 64;
  const int wn = (w >> 1) * 64;

  const int off0 = t * 8, off1 = t * 8 + 2048;
  const int ar0 = off0 >> 5, ac0 = (((off0 >> 3) & 3) ^ ((ar0 >> 1) & 3)) * 8;
  const int ar1 = off1 >> 5, ac1 = (((off1 >> 3) & 3) ^ ((ar1 >> 1) & 3)) * 8;
  const unsigned short* Ag0 = A + (size_t)(m0 + ar0) * K + ac0;
  const unsigned short* Ag1 = A + (size_t)(m0 + ar1) * K + ac1;
  const unsigned short* Wg0 = W + (size_t)(n0 + ar0) * K + ac0;
  const unsigned short* Wg1 = W + (size_t)(n0 + ar1) * K + ac1;
  unsigned short* sA0 = &sA[w * 512];
  unsigned short* sA1 = &sA[2048 + w * 512];
  unsigned short* sB0 = &sB[w * 512];
  unsigned short* sB1 = &sB[2048 + w * 512];

  f32x4 acc[4][4] = {};

  for (int kt = 0; kt < K; kt += 32) {
    gload16(Ag0 + kt, sA0);
    gload16(Ag1 + kt, sA1);
    gload16(Wg0 + kt, sB0);
    gload16(Wg1 + kt, sB1);
    __syncthreads();
    bf16x8 af[4], bf[4];
#pragma unroll
    for (int mi = 0; mi < 4; ++mi) {
      int row = wm + mi * 16 + lm;
      af[mi] = *(const bf16x8*)&sA[row * 32 + ((quad ^ ((row >> 1) & 3)) << 3)];
    }
#pragma unroll
    for (int ni = 0; ni < 4; ++ni) {
      int row = wn + ni * 16 + lm;
      bf[ni] = *(const bf16x8*)&sB[row * 32 + ((quad ^ ((row >> 1) & 3)) << 3)];
    }
#pragma unroll
    for (int mi = 0; mi < 4; ++mi)
#pragma unroll
      for (int ni = 0; ni < 4; ++ni)
        acc[mi][ni] = __builtin_amdgcn_mfma_f32_16x16x32_bf16(af[mi], bf[ni], acc[mi][ni], 0, 0, 0);
    __syncthreads();
  }

#pragma unroll
  for (int mi = 0; mi < 4; ++mi)
#pragma unroll
    for (int ni = 0; ni < 4; ++ni) {
      int col = n0 + wn + ni * 16 + lm;
      float bv = bias[col];
      float v0 = acc[mi][ni][0] + bv, v1 = acc[mi][ni][1] + bv;
      float v2 = acc[mi][ni][2] + bv, v3 = acc[mi][ni][3] + bv;
      int rbase = m0 + wm + mi * 16 + quad * 4;
      if (mode == 0) {
        float* op = (float*)Cout;
        op[(size_t)(rbase + 0) * N + col] = v0;
        op[(size_t)(rbase + 1) * N + col] = v1;
        op[(size_t)(rbase + 2) * N + col] = v2;
        op[(size_t)(rbase + 3) * N + col] = v3;
      } else if (col < 2048) {
        unsigned short* op = (unsigned short*)Cout;
        op[(size_t)(rbase + 0) * QK_LD + col] = f2bf(v0);
        op[(size_t)(rbase + 1) * QK_LD + col] = f2bf(v1);
        op[(size_t)(rbase + 2) * QK_LD + col] = f2bf(v2);
        op[(size_t)(rbase + 3) * QK_LD + col] = f2bf(v3);
      } else {
        int c = col - 2048;
        int bh = (m0 >> 11) * 16 + (c >> 6);
        int hd = c & 63;
        int sbase = (rbase & 2047);
        uint2 pk = {pkbf(v0, v1), pkbf(v2, v3)};
        *(uint2*)(vt + (size_t)bh * (HD_ * S_) + (size_t)hd * S_ + sbase) = pk;
      }
    }
}

// ---------------- flash attention (R13: 8 waves x 32 q-rows, unchanged) ----------------
__global__ __launch_bounds__(512, 4) void attn_kernel(
    const unsigned short* __restrict__ qk, const unsigned short* __restrict__ vt,
    unsigned short* __restrict__ ab) {
  __shared__ __attribute__((aligned(16))) unsigned short sK[2][64 * 64];
  __shared__ __attribute__((aligned(16))) unsigned short sV[2][64 * 64];  // [hd][n]
  __shared__ __attribute__((aligned(16))) unsigned short sP[8][32 * 64];  // 4KB/wave

  const int t = threadIdx.x;
  const int lane = t & 63;
  const int w = t >> 6;  // 0..7
  const int lm = lane & 15;
  const int quad = lane >> 4;
  const int bh = blockIdx.x & 63;
  const int b = bh >> 4, h = bh & 15;
  const int q0 = (blockIdx.x >> 6) * 256;

  const unsigned short* qg = qk + (size_t)b * S_ * QK_LD + h * HD_;
  const unsigned short* kg = qg + 1024;
  const unsigned short* vg = vt + (size_t)bh * HD_ * S_;

  const int r0 = t >> 3;
  const int c0 = ((t & 7) ^ (r0 & 7)) * 8;

  gload16(kg + (size_t)r0 * QK_LD + c0, &sK[0][w * 512]);
  gload16(vg + (size_t)r0 * S_ + c0, &sV[0][w * 512]);

  bf16x8 qf[2][2];
#pragma unroll
  for (int mi = 0; mi < 2; ++mi) {
    int row = q0 + w * 32 + mi * 16 + lm;
#pragma unroll
    for (int kc = 0; kc < 2; ++kc)
      qf[mi][kc] = *(const bf16x8*)(qg + (size_t)row * QK_LD + kc * 32 + quad * 8);
  }
  __syncthreads();  // K0/V0 staged

  unsigned short* sPw = sP[w];
  const bf16x8 ones = __builtin_bit_cast(bf16x8, (short8)(short)0x3F80);  // 1.0 bf16
  f32x4 o[2][4] = {};
  f32x4 Lacc[2] = {};

  for (int n0 = 0; n0 < S_; n0 += 64) {
    const int cur = (n0 >> 6) & 1, nxt = cur ^ 1;
    if (n0 + 64 < S_) {  // prefetch next K/V tile (wave-uniform branch)
      gload16(kg + (size_t)(n0 + 64 + r0) * QK_LD + c0, &sK[nxt][w * 512]);
      gload16(vg + (size_t)r0 * S_ + (n0 + 64) + c0, &sV[nxt][w * 512]);
    }

    f32x4 s[2][4] = {};
#pragma unroll
    for (int kc = 0; kc < 2; ++kc)
#pragma unroll
      for (int nb = 0; nb < 4; ++nb) {
        int row = nb * 16 + lm;
        bf16x8 kf = *(const bf16x8*)&sK[cur][row * 64 + (((kc * 4 + quad) ^ (row & 7)) << 3)];
#pragma unroll
        for (int mi = 0; mi < 2; ++mi)
          s[mi][nb] = __builtin_amdgcn_mfma_f32_16x16x32_bf16(kf, qf[mi][kc], s[mi][nb], 0, 0, 0);
      }

#pragma unroll
    for (int mi = 0; mi < 2; ++mi) {
      int prow = mi * 16 + lm;
      char* rowp = (char*)sPw + prow * 128;
#pragma unroll
      for (int nb = 0; nb < 4; ++nb) {
        const f32x4& sv = s[mi][nb];
        uint2 pk = {pkbf(__builtin_amdgcn_exp2f(sv[0]), __builtin_amdgcn_exp2f(sv[1])),
                    pkbf(__builtin_amdgcn_exp2f(sv[2]), __builtin_amdgcn_exp2f(sv[3]))};
        int c16 = (nb * 2 + (quad >> 1)) ^ (prow & 7);
        *(uint2*)(rowp + (c16 << 4) + ((quad & 1) << 3)) = pk;
      }
    }

#pragma unroll
    for (int kc = 0; kc < 2; ++kc) {
      bf16x8 pf[2];
#pragma unroll
      for (int mi = 0; mi < 2; ++mi) {
        int prow = mi * 16 + lm;
        pf[mi] = *(const bf16x8*)&sPw[prow * 64 + (((kc * 4 + quad) ^ (prow & 7)) << 3)];
        Lacc[mi] = __builtin_amdgcn_mfma_f32_16x16x32_bf16(pf[mi], ones, Lacc[mi], 0, 0, 0);
      }
#pragma unroll
      for (int nf = 0; nf < 4; ++nf) {
        int row = nf * 16 + lm;
        bf16x8 vf = *(const bf16x8*)&sV[cur][row * 64 + (((kc * 4 + quad) ^ (row & 7)) << 3)];
#pragma unroll
        for (int mi = 0; mi < 2; ++mi)
          o[mi][nf] = __builtin_amdgcn_mfma_f32_16x16x32_bf16(pf[mi], vf, o[mi][nf], 0, 0, 0);
      }
    }
    __syncthreads();
  }

#pragma unroll
  for (int mi = 0; mi < 2; ++mi)
#pragma unroll
    for (int r = 0; r < 4; ++r) {
      float rinv = 1.0f / Lacc[mi][r];
      int row = q0 + w * 32 + mi * 16 + quad * 4 + r;
#pragma unroll
      for (int nf = 0; nf < 4; ++nf) {
        int col = h * HD_ + nf * 16 + lm;
        ab[(size_t)(b * S_ + row) * D_ + col] = f2bf(o[mi][nf][r] * rinv);
      }
    }
}

extern "C" void kernel_launch(void* const* d_in, const int* in_sizes, int n_in,
                              void* d_out, int out_size, void* d_ws, size_t ws_size,
                              hipStream_t stream) {
  const float* x = (const float*)d_in[0];
  const float* Wq = (const float*)d_in[1];
  const float* bq = (const float*)d_in[2];
  const float* Wk = (const float*)d_in[3];
  const float* bk = (const float*)d_in[4];
  const float* Wv = (const float*)d_in[5];
  const float* bv = (const float*)d_in[6];
  const float* Wo = (const float*)d_in[7];
  const float* bo = (const float*)d_in[8];
  float* out = (float*)d_out;

  const size_t E = (size_t)B_ * S_ * D_;   // 8388608
  const size_t WE = (size_t)D_ * D_;       // 1048576
  unsigned short* xb = (unsigned short*)d_ws;
  unsigned short* wcat = xb + E;
  unsigned short* wob = wcat + 3 * WE;
  float* bcat = (float*)(wcat + 4 * WE);
  unsigned short* qkb = (unsigned short*)(bcat + 4096);
  unsigned short* vtb = qkb + (size_t)B_ * S_ * QK_LD;
  unsigned short* abuf = xb;  // reuse: x consumed by QKV gemm before attention writes

  cvt_all<<<dim3(6145), 256, 0, stream>>>(x, Wq, Wk, Wv, Wo, bq, bk, bv, xb, wcat, bcat);

  gemm_qkv_256<<<dim3(384), 512, 0, stream>>>(xb, wcat, bcat, qkb, vtb);
  attn_kernel<<<dim3(512), 512, 0, stream>>>(qkb, vtb, abuf);
  gemm_bt<<<dim3((B_ * S_) / 128, D_ / 128), 256, 0, stream>>>(
      abuf, wob, bo, out, nullptr, B_ * S_, D_, D_, 0);
}

// Round 6
// 276.057 us; speedup vs baseline: 1.0268x; 1.0015x over previous
//
#include <hip/hip_runtime.h>
#include <cstdint>

// MultiHeadAttention: B=4, S=2048, D=1024, H=16, HD=64. fp32 in/out, bf16 MFMA compute.
// R15: (1) gemm_qkv REVERTED to R10 4-phase GROUP (R14's 2-fat-phase flatten regressed
// 81->102us: phase-interleave, not barrier count, is the value); (2) out-proj rewritten
// as 4-phase BM=256/BN=128 (grid 256 = exactly 1 round, R10-style per-quarter stage
// windows); (3) cvt_all fusion kept (measured ~-27us: launch gaps ~10us each).
// attn = R13 8-wave/32-row (kept).

#define B_ 4
#define S_ 2048
#define D_ 1024
#define H_ 16
#define HD_ 64
#define QKV_N 3072
#define QK_LD 2048  // q|k buffer row stride (V lives in vt)
#define SCALE_Q 0.18033688011111772f  // 0.125 * log2(e)

typedef __bf16 bf16x8 __attribute__((ext_vector_type(8)));
typedef __bf16 bf16x2 __attribute__((ext_vector_type(2)));
typedef float f32x4 __attribute__((ext_vector_type(4)));
typedef short short8 __attribute__((ext_vector_type(8)));

__device__ __forceinline__ unsigned short f2bf(float f) {
  unsigned int u = __builtin_bit_cast(unsigned int, f);
  u = (u + 0x7FFFu + ((u >> 16) & 1u)) >> 16;  // RNE
  return (unsigned short)u;
}

__device__ __forceinline__ unsigned int pkbf(float a, float b) {
  bf16x2 v;
  v.x = (__bf16)a;
  v.y = (__bf16)b;
  return __builtin_bit_cast(unsigned int, v);
}

__device__ __forceinline__ void gload16(const void* g, void* l) {
  __builtin_amdgcn_global_load_lds(
      (const __attribute__((address_space(1))) void*)g,
      (__attribute__((address_space(3))) void*)l, 16, 0, 0);
}

// Fused elementwise front-end: blocks [0,4096) cvt x -> bf16; [4096,6144) cvt 4 W mats;
// block 6144 builds bias_cat.
__global__ __launch_bounds__(256) void cvt_all(
    const float* __restrict__ x, const float* __restrict__ w0, const float* __restrict__ w1,
    const float* __restrict__ w2, const float* __restrict__ w3,
    const float* __restrict__ bq, const float* __restrict__ bk, const float* __restrict__ bv,
    unsigned short* __restrict__ xb, unsigned short* __restrict__ wcat,
    float* __restrict__ bcat) {
  const int blk = blockIdx.x;
  const int t = threadIdx.x;
  if (blk < 4096) {
    size_t i = (size_t)blk * 256 + t;
    const float4* p = (const float4*)x + i * 2;
    float4 a = p[0], b = p[1];
    unsigned short o[8] = {f2bf(a.x), f2bf(a.y), f2bf(a.z), f2bf(a.w),
                           f2bf(b.x), f2bf(b.y), f2bf(b.z), f2bf(b.w)};
    *(uint4*)(xb + i * 8) = *(const uint4*)o;
  } else if (blk < 6144) {
    int y = (blk - 4096) >> 9;
    const float* src = (y == 0) ? w0 : (y == 1) ? w1 : (y == 2) ? w2 : w3;
    float s = (y == 0) ? SCALE_Q : 1.0f;
    size_t i = (size_t)((blk - 4096) & 511) * 256 + t;
    const float4* p = (const float4*)src + i * 2;
    float4 a = p[0], b = p[1];
    unsigned short o[8] = {f2bf(a.x * s), f2bf(a.y * s), f2bf(a.z * s), f2bf(a.w * s),
                           f2bf(b.x * s), f2bf(b.y * s), f2bf(b.z * s), f2bf(b.w * s)};
    *(uint4*)(wcat + (size_t)y * 1048576 + i * 8) = *(const uint4*)o;
  } else {
    for (int i = t; i < 3072; i += 256) {
      float v = (i < 1024) ? bq[i] * SCALE_Q : (i < 2048) ? bk[i - 1024] : bv[i - 2048];
      bcat[i] = v;
    }
  }
}

// ---------------- shared GEMM helpers ----------------
__device__ __forceinline__ void ld_afrag(const unsigned short* s, int rowbase, int quad,
                                         int sw, bf16x8 af[4][2]) {
#pragma unroll
  for (int mi2 = 0; mi2 < 4; ++mi2) {
    int row = rowbase + mi2 * 16;
#pragma unroll
    for (int kk = 0; kk < 2; ++kk)
      af[mi2][kk] = *(const bf16x8*)&s[row * 64 + ((((kk << 2) + quad) ^ sw) << 3)];
  }
}

__device__ __forceinline__ void ld_bfrag(const unsigned short* s, int rowbase, int quad,
                                         int sw, bf16x8 bf[2][2]) {
#pragma unroll
  for (int ni2 = 0; ni2 < 2; ++ni2) {
    int row = rowbase + ni2 * 16;
#pragma unroll
    for (int kk = 0; kk < 2; ++kk)
      bf[ni2][kk] = *(const bf16x8*)&s[row * 64 + ((((kk << 2) + quad) ^ sw) << 3)];
  }
}

__device__ __forceinline__ void ld_b2(const unsigned short* s, int row, int quad,
                                      int sw, bf16x8 bf[2]) {
#pragma unroll
  for (int kk = 0; kk < 2; ++kk)
    bf[kk] = *(const bf16x8*)&s[row * 64 + ((((kk << 2) + quad) ^ sw) << 3)];
}

#define SBAR() __builtin_amdgcn_sched_barrier(0)
#define BARRIER()                      \
  do {                                 \
    SBAR();                            \
    __builtin_amdgcn_s_barrier();      \
    SBAR();                            \
  } while (0)
#define WAITLGKM()                                      \
  do {                                                  \
    asm volatile("s_waitcnt lgkmcnt(0)" ::: "memory");  \
    SBAR();                                             \
  } while (0)

// ---------------- 256x256 8-phase QKV GEMM (R10, verified @81us) ----------------
#define MM(qm, qn, BF)                                                                   \
  _Pragma("unroll") for (int mi2 = 0; mi2 < 4; ++mi2)                                    \
  _Pragma("unroll") for (int ni2 = 0; ni2 < 2; ++ni2)                                    \
  _Pragma("unroll") for (int kk = 0; kk < 2; ++kk)                                       \
      acc[(qm) * 4 + mi2][(qn) * 2 + ni2] = __builtin_amdgcn_mfma_f32_16x16x32_bf16(     \
          af[mi2][kk], BF[ni2][kk], acc[(qm) * 4 + mi2][(qn) * 2 + ni2], 0, 0, 0);

__global__ __launch_bounds__(512, 2) void gemm_qkv_256(
    const unsigned short* __restrict__ A, const unsigned short* __restrict__ W,
    const float* __restrict__ bias, unsigned short* __restrict__ qk,
    unsigned short* __restrict__ vt) {
  __shared__ __attribute__((aligned(16))) unsigned short sA[2][256 * 64];
  __shared__ __attribute__((aligned(16))) unsigned short sB[2][256 * 64];

  const int t = threadIdx.x;
  const int lane = t & 63;
  const int w = t >> 6;
  const int lm = lane & 15;
  const int quad = lane >> 4;
  const int sw = lm & 7;
  const int wm = (w >> 2) * 128;
  const int wn = (w & 3) * 64;

  const int bid = blockIdx.x;
  const int xcd = bid & 7, lin = bid >> 3;
  const int mt = xcd * 4 + (lin & 3);
  const int nt = lin >> 2;
  const int m0 = mt * 256, n0 = nt * 256;
  const int K = 1024;

  const int srow = t >> 3;
  const int scol = ((t & 7) ^ ((t >> 3) & 7)) << 3;
  const unsigned short* Ab = A + ((size_t)m0 + srow) * K + scol;
  const unsigned short* Wb = W + ((size_t)n0 + srow) * K + scol;

#define STG_A(bb, q, kt) gload16(Ab + (size_t)((q) * 64) * K + (kt), &sA[bb][(q) * 4096 + w * 512])
#define STG_B(bb, q, kt) gload16(Wb + (size_t)((q) * 64) * K + (kt), &sB[bb][(q) * 4096 + w * 512])

  STG_A(0, 0, 0); STG_A(0, 1, 0); STG_A(0, 2, 0); STG_A(0, 3, 0);
  STG_B(0, 0, 0); STG_B(0, 1, 0); STG_B(0, 2, 0); STG_B(0, 3, 0);
  STG_A(1, 0, 64); STG_A(1, 2, 64);
  STG_B(1, 0, 64); STG_B(1, 1, 64);
  STG_A(1, 1, 64); STG_A(1, 3, 64);
  asm volatile("s_waitcnt vmcnt(6)" ::: "memory");
  BARRIER();

  f32x4 acc[8][4] = {};
  bf16x8 af[4][2], bf0[2][2], bf1[2][2];

#define GROUP(c, kn1, kn2)                                                            \
  do {                                                                                \
    ld_afrag(sA[c], wm + lm, quad, sw, af);                                           \
    ld_bfrag(sB[c], wn + lm, quad, sw, bf0);                                          \
    STG_B(c ^ 1, 2, kn1);                                                             \
    STG_B(c ^ 1, 3, kn1);                                                             \
    BARRIER(); WAITLGKM();                                                            \
    __builtin_amdgcn_s_setprio(1); MM(0, 0, bf0); __builtin_amdgcn_s_setprio(0);      \
    BARRIER();                                                                        \
    ld_bfrag(sB[c], wn + 32 + lm, quad, sw, bf1);                                     \
    STG_A(c, 0, kn2);                                                                 \
    STG_A(c, 2, kn2);                                                                 \
    BARRIER(); WAITLGKM();                                                            \
    __builtin_amdgcn_s_setprio(1); MM(0, 1, bf1); __builtin_amdgcn_s_setprio(0);      \
    BARRIER();                                                                        \
    ld_afrag(sA[c], wm + 64 + lm, quad, sw, af);                                      \
    STG_B(c, 0, kn2);                                                                 \
    STG_B(c, 1, kn2);                                                                 \
    BARRIER(); WAITLGKM();                                                            \
    __builtin_amdgcn_s_setprio(1); MM(1, 0, bf0); __builtin_amdgcn_s_setprio(0);      \
    BARRIER();                                                                        \
    STG_A(c, 1, kn2);                                                                 \
    STG_A(c, 3, kn2);                                                                 \
    asm volatile("s_waitcnt vmcnt(6)" ::: "memory");                                  \
    BARRIER();                                                                        \
    __builtin_amdgcn_s_setprio(1); MM(1, 1, bf1); __builtin_amdgcn_s_setprio(0);      \
    BARRIER();                                                                        \
  } while (0)

  for (int kt = 0; kt < K; kt += 128) {
    const int kn1a = kt + 64;
    const int kn2a = (kt + 128 < K) ? kt + 128 : K - 64;
    const int kn1b = kn2a;
    const int kn2b = (kt + 192 < K) ? kt + 192 : K - 64;
    GROUP(0, kn1a, kn2a);
    GROUP(1, kn1b, kn2b);
  }

  asm volatile("s_waitcnt vmcnt(0)" ::: "memory");

#pragma unroll
  for (int mi = 0; mi < 8; ++mi) {
    const int rbase = m0 + wm + mi * 16 + quad * 4;
#pragma unroll
    for (int ni = 0; ni < 4; ++ni) {
      const int col = n0 + wn + ni * 16 + lm;
      const float bv = bias[col];
      float v0 = acc[mi][ni][0] + bv, v1 = acc[mi][ni][1] + bv;
      float v2 = acc[mi][ni][2] + bv, v3 = acc[mi][ni][3] + bv;
      if (n0 < 2048) {
        qk[(size_t)(rbase + 0) * QK_LD + col] = f2bf(v0);
        qk[(size_t)(rbase + 1) * QK_LD + col] = f2bf(v1);
        qk[(size_t)(rbase + 2) * QK_LD + col] = f2bf(v2);
        qk[(size_t)(rbase + 3) * QK_LD + col] = f2bf(v3);
      } else {
        int c2 = col - 2048;
        int bh = (m0 >> 11) * 16 + (c2 >> 6);
        int hd = c2 & 63;
        int sbase = rbase & 2047;
        uint2 pk = {pkbf(v0, v1), pkbf(v2, v3)};
        *(uint2*)(vt + (size_t)bh * (HD_ * S_) + (size_t)hd * S_ + sbase) = pk;
      }
    }
  }
}

// ---------------- out-proj GEMM: 256x128, 4-phase, grid 256 = exactly 1 round ----------------
// C[m,n] = sum_k A[m,k]*W[n,k] + bias[n] (fp32 out). M=8192, N=1024, K=1024.
// 8 waves 2Mx4N, per-wave 128x32 (acc[8][2]); LDS A 64KB + B 32KB = 96KB dbuf.
// Per tile (6 loads: A q0-q3, B q0-q1), R10-style windows:
//  p1: ld A-qm0 (8) + B-ni0 (2); stage B0B1(T+1)->c^1;  MM(qm0,ni0) 8
//  p2: ld B-ni1 (2);            stage A0A2(T+2)->c;     MM(qm0,ni1) 8   [q0,q2 freed by p1]
//  p3: ld A-qm1 (8);                                    MM(qm1,ni0) 8
//  p4: stage A1A3(T+2)->c; vmcnt(4) [outstanding = 4 T+2 A-loads -> T+1 fully resident];
//      BARRIER publishes T+1;                           MM(qm1,ni1) 8   [q1,q3 freed by p3]
#define MM8(qm, ni, BF)                                                                  \
  _Pragma("unroll") for (int mi2 = 0; mi2 < 4; ++mi2)                                    \
  _Pragma("unroll") for (int kk = 0; kk < 2; ++kk)                                       \
      acc[(qm) * 4 + mi2][ni] = __builtin_amdgcn_mfma_f32_16x16x32_bf16(                 \
          af[mi2][kk], BF[kk], acc[(qm) * 4 + mi2][ni], 0, 0, 0);

__global__ __launch_bounds__(512, 2) void gemm_out_256(
    const unsigned short* __restrict__ A, const unsigned short* __restrict__ W,
    const float* __restrict__ bias, float* __restrict__ out) {
  __shared__ __attribute__((aligned(16))) unsigned short sA[2][256 * 64];  // 64KB
  __shared__ __attribute__((aligned(16))) unsigned short sB[2][128 * 64];  // 32KB

  const int t = threadIdx.x;
  const int lane = t & 63;
  const int w = t >> 6;
  const int lm = lane & 15;
  const int quad = lane >> 4;
  const int sw = lm & 7;
  const int wm = (w >> 2) * 128;
  const int wn = (w & 3) * 32;

  // grid 256 = 8 XCD x 32; per XCD 4 m-tiles x 8 n-tiles
  const int bid = blockIdx.x;
  const int xcd = bid & 7, lin = bid >> 3;
  const int mt = xcd * 4 + (lin & 3);
  const int nt = lin >> 2;  // 0..7
  const int m0 = mt * 256, n0 = nt * 128;
  const int K = 1024;

  const int srow = t >> 3;
  const int scol = ((t & 7) ^ ((t >> 3) & 7)) << 3;
  const unsigned short* Ab = A + ((size_t)m0 + srow) * K + scol;
  const unsigned short* Wb = W + ((size_t)n0 + srow) * K + scol;

#define OSTG_A(bb, q, kt) gload16(Ab + (size_t)((q) * 64) * K + (kt), &sA[bb][(q) * 4096 + w * 512])
#define OSTG_B(bb, q, kt) gload16(Wb + (size_t)((q) * 64) * K + (kt), &sB[bb][(q) * 4096 + w * 512])

  // prologue: tile0 full (6) + tile1 A (4); vmcnt(4) -> tile0 resident
  OSTG_A(0, 0, 0); OSTG_A(0, 1, 0); OSTG_A(0, 2, 0); OSTG_A(0, 3, 0);
  OSTG_B(0, 0, 0); OSTG_B(0, 1, 0);
  OSTG_A(1, 0, 64); OSTG_A(1, 2, 64);
  OSTG_A(1, 1, 64); OSTG_A(1, 3, 64);
  asm volatile("s_waitcnt vmcnt(4)" ::: "memory");
  BARRIER();

  f32x4 acc[8][2] = {};
  bf16x8 af[4][2], bf0[2], bf1[2];

  for (int tt = 0; tt < 16; ++tt) {
    const int c = tt & 1;
    const int knB = (tt + 1 < 16 ? tt + 1 : 15) * 64;  // B of T+1 (clamped)
    const int knA = (tt + 2 < 16 ? tt + 2 : 15) * 64;  // A of T+2 (clamped)
    // p1
    ld_afrag(sA[c], wm + lm, quad, sw, af);
    ld_b2(sB[c], wn + lm, quad, sw, bf0);
    OSTG_B(c ^ 1, 0, knB);
    OSTG_B(c ^ 1, 1, knB);
    BARRIER(); WAITLGKM();
    __builtin_amdgcn_s_setprio(1); MM8(0, 0, bf0); __builtin_amdgcn_s_setprio(0);
    BARRIER();
    // p2
    ld_b2(sB[c], wn + 16 + lm, quad, sw, bf1);
    OSTG_A(c, 0, knA);
    OSTG_A(c, 2, knA);
    BARRIER(); WAITLGKM();
    __builtin_amdgcn_s_setprio(1); MM8(0, 1, bf1); __builtin_amdgcn_s_setprio(0);
    BARRIER();
    // p3
    ld_afrag(sA[c], wm + 64 + lm, quad, sw, af);
    BARRIER(); WAITLGKM();
    __builtin_amdgcn_s_setprio(1); MM8(1, 0, bf0); __builtin_amdgcn_s_setprio(0);
    BARRIER();
    // p4
    OSTG_A(c, 1, knA);
    OSTG_A(c, 3, knA);
    asm volatile("s_waitcnt vmcnt(4)" ::: "memory");  // T+1 fully resident
    BARRIER();
    __builtin_amdgcn_s_setprio(1); MM8(1, 1, bf1); __builtin_amdgcn_s_setprio(0);
    BARRIER();
  }

  asm volatile("s_waitcnt vmcnt(0)" ::: "memory");

#pragma unroll
  for (int mi = 0; mi < 8; ++mi) {
    const int rbase = m0 + wm + mi * 16 + quad * 4;
#pragma unroll
    for (int ni = 0; ni < 2; ++ni) {
      const int col = n0 + wn + ni * 16 + lm;
      const float bv = bias[col];
      out[(size_t)(rbase + 0) * D_ + col] = acc[mi][ni][0] + bv;
      out[(size_t)(rbase + 1) * D_ + col] = acc[mi][ni][1] + bv;
      out[(size_t)(rbase + 2) * D_ + col] = acc[mi][ni][2] + bv;
      out[(size_t)(rbase + 3) * D_ + col] = acc[mi][ni][3] + bv;
    }
  }
}

// ---------------- flash attention (R13: 8 waves x 32 q-rows, unchanged) ----------------
__global__ __launch_bounds__(512, 4) void attn_kernel(
    const unsigned short* __restrict__ qk, const unsigned short* __restrict__ vt,
    unsigned short* __restrict__ ab) {
  __shared__ __attribute__((aligned(16))) unsigned short sK[2][64 * 64];
  __shared__ __attribute__((aligned(16))) unsigned short sV[2][64 * 64];  // [hd][n]
  __shared__ __attribute__((aligned(16))) unsigned short sP[8][32 * 64];  // 4KB/wave

  const int t = threadIdx.x;
  const int lane = t & 63;
  const int w = t >> 6;  // 0..7
  const int lm = lane & 15;
  const int quad = lane >> 4;
  const int bh = blockIdx.x & 63;
  const int b = bh >> 4, h = bh & 15;
  const int q0 = (blockIdx.x >> 6) * 256;

  const unsigned short* qg = qk + (size_t)b * S_ * QK_LD + h * HD_;
  const unsigned short* kg = qg + 1024;
  const unsigned short* vg = vt + (size_t)bh * HD_ * S_;

  const int r0 = t >> 3;
  const int c0 = ((t & 7) ^ (r0 & 7)) * 8;

  gload16(kg + (size_t)r0 * QK_LD + c0, &sK[0][w * 512]);
  gload16(vg + (size_t)r0 * S_ + c0, &sV[0][w * 512]);

  bf16x8 qf[2][2];
#pragma unroll
  for (int mi = 0; mi < 2; ++mi) {
    int row = q0 + w * 32 + mi * 16 + lm;
#pragma unroll
    for (int kc = 0; kc < 2; ++kc)
      qf[mi][kc] = *(const bf16x8*)(qg + (size_t)row * QK_LD + kc * 32 + quad * 8);
  }
  __syncthreads();  // K0/V0 staged

  unsigned short* sPw = sP[w];
  const bf16x8 ones = __builtin_bit_cast(bf16x8, (short8)(short)0x3F80);  // 1.0 bf16
  f32x4 o[2][4] = {};
  f32x4 Lacc[2] = {};

  for (int n0 = 0; n0 < S_; n0 += 64) {
    const int cur = (n0 >> 6) & 1, nxt = cur ^ 1;
    if (n0 + 64 < S_) {  // wave-uniform
      gload16(kg + (size_t)(n0 + 64 + r0) * QK_LD + c0, &sK[nxt][w * 512]);
      gload16(vg + (size_t)r0 * S_ + (n0 + 64) + c0, &sV[nxt][w * 512]);
    }

    f32x4 s[2][4] = {};
#pragma unroll
    for (int kc = 0; kc < 2; ++kc)
#pragma unroll
      for (int nb = 0; nb < 4; ++nb) {
        int row = nb * 16 + lm;
        bf16x8 kf = *(const bf16x8*)&sK[cur][row * 64 + (((kc * 4 + quad) ^ (row & 7)) << 3)];
#pragma unroll
        for (int mi = 0; mi < 2; ++mi)
          s[mi][nb] = __builtin_amdgcn_mfma_f32_16x16x32_bf16(kf, qf[mi][kc], s[mi][nb], 0, 0, 0);
      }

#pragma unroll
    for (int mi = 0; mi < 2; ++mi) {
      int prow = mi * 16 + lm;
      char* rowp = (char*)sPw + prow * 128;
#pragma unroll
      for (int nb = 0; nb < 4; ++nb) {
        const f32x4& sv = s[mi][nb];
        uint2 pk = {pkbf(__builtin_amdgcn_exp2f(sv[0]), __builtin_amdgcn_exp2f(sv[1])),
                    pkbf(__builtin_amdgcn_exp2f(sv[2]), __builtin_amdgcn_exp2f(sv[3]))};
        int c16 = (nb * 2 + (quad >> 1)) ^ (prow & 7);
        *(uint2*)(rowp + (c16 << 4) + ((quad & 1) << 3)) = pk;
      }
    }

#pragma unroll
    for (int kc = 0; kc < 2; ++kc) {
      bf16x8 pf[2];
#pragma unroll
      for (int mi = 0; mi < 2; ++mi) {
        int prow = mi * 16 + lm;
        pf[mi] = *(const bf16x8*)&sPw[prow * 64 + (((kc * 4 + quad) ^ (prow & 7)) << 3)];
        Lacc[mi] = __builtin_amdgcn_mfma_f32_16x16x32_bf16(pf[mi], ones, Lacc[mi], 0, 0, 0);
      }
#pragma unroll
      for (int nf = 0; nf < 4; ++nf) {
        int row = nf * 16 + lm;
        bf16x8 vf = *(const bf16x8*)&sV[cur][row * 64 + (((kc * 4 + quad) ^ (row & 7)) << 3)];
#pragma unroll
        for (int mi = 0; mi < 2; ++mi)
          o[mi][nf] = __builtin_amdgcn_mfma_f32_16x16x32_bf16(pf[mi], vf, o[mi][nf], 0, 0, 0);
      }
    }
    __syncthreads();
  }

#pragma unroll
  for (int mi = 0; mi < 2; ++mi)
#pragma unroll
    for (int r = 0; r < 4; ++r) {
      float rinv = 1.0f / Lacc[mi][r];
      int row = q0 + w * 32 + mi * 16 + quad * 4 + r;
#pragma unroll
      for (int nf = 0; nf < 4; ++nf) {
        int col = h * HD_ + nf * 16 + lm;
        ab[(size_t)(b * S_ + row) * D_ + col] = f2bf(o[mi][nf][r] * rinv);
      }
    }
}

extern "C" void kernel_launch(void* const* d_in, const int* in_sizes, int n_in,
                              void* d_out, int out_size, void* d_ws, size_t ws_size,
                              hipStream_t stream) {
  const float* x = (const float*)d_in[0];
  const float* Wq = (const float*)d_in[1];
  const float* bq = (const float*)d_in[2];
  const float* Wk = (const float*)d_in[3];
  const float* bk = (const float*)d_in[4];
  const float* Wv = (const float*)d_in[5];
  const float* bv = (const float*)d_in[6];
  const float* Wo = (const float*)d_in[7];
  const float* bo = (const float*)d_in[8];
  float* out = (float*)d_out;

  const size_t E = (size_t)B_ * S_ * D_;   // 8388608
  const size_t WE = (size_t)D_ * D_;       // 1048576
  unsigned short* xb = (unsigned short*)d_ws;
  unsigned short* wcat = xb + E;
  unsigned short* wob = wcat + 3 * WE;
  float* bcat = (float*)(wcat + 4 * WE);
  unsigned short* qkb = (unsigned short*)(bcat + 4096);
  unsigned short* vtb = qkb + (size_t)B_ * S_ * QK_LD;
  unsigned short* abuf = xb;  // reuse: x consumed by QKV gemm before attention writes

  cvt_all<<<dim3(6145), 256, 0, stream>>>(x, Wq, Wk, Wv, Wo, bq, bk, bv, xb, wcat, bcat);

  gemm_qkv_256<<<dim3(384), 512, 0, stream>>>(xb, wcat, bcat, qkb, vtb);
  attn_kernel<<<dim3(512), 512, 0, stream>>>(qkb, vtb, abuf);
  gemm_out_256<<<dim3(256), 512, 0, stream>>>(abuf, wob, bo, out);
}